// Round 9
// baseline (135.056 us; speedup 1.0000x reference)
//
#include <hip/hip_runtime.h>
#include <hip/hip_bf16.h>

// RestrictedNN DAG. Round 13: R10b (best, 117.6) + 2 batch tiles per block.
//  - R12's lesson (with R7/R11): every cross-block global handoff costs more
//    than the 5us k_root. Three-kernel structure is final; k_root stays.
//  - k_tree grid 2048 -> 1024: each block processes two consecutive batch
//    tiles for its slice s. Weights w1r/w2r loaded ONCE (regs, reused);
//    tile-1 x issued as raw float4s right after tile-0's LDS write (lands
//    under tile-0 compute); W0f re-read for tile 1 is same-block L2-hot.
//    Cuts block generations 2.67 -> 1.33, amortizing per-block fixed cost.
//  - Phases A/B/C byte-identical to R10b per tile -> absmax unchanged.
// B=4096, L0=512 leaves (G=8,H=16), L1=64, L2=8 (FAN=8), root 128->16.

#define TB 16
#define H1S 136      // ushorts per h1 row (128+8): rows 16B-aligned

typedef __attribute__((ext_vector_type(8))) short short8;
typedef __attribute__((ext_vector_type(4))) float floatx4;

__device__ __forceinline__ float sigf(float v) {
    return __builtin_amdgcn_rcpf(1.0f + __expf(-v));
}
// packed f32x2 -> bf16x2 (RNE). Compiler emits v_cvt_pk_bf16_f32.
__device__ __forceinline__ unsigned int f2bf2(float lo, float hi) {
    __hip_bfloat162 p = __float22bfloat162_rn(make_float2(lo, hi));
    unsigned int u;
    __builtin_memcpy(&u, &p, 4);
    return u;
}
__device__ __forceinline__ unsigned short f2bf(float f) {
    __hip_bfloat16 b = __float2bfloat16(f);
    unsigned short u;
    __builtin_memcpy(&u, &b, 2);
    return u;
}

// ---- prep ----
// blocks 0..71 : transpose W1/W2 per module to bf16 [h][k] fragment layout
// blocks 72..135: build W0f (per-module 64-lane A-frag table, bf16 Wg*W0,
//                zero K-pad) and bias0 (f32, = bg . W0)
__global__ __launch_bounds__(256) void k_prep(
    const float* __restrict__ W1, const float* __restrict__ W2,
    const float* __restrict__ Wg, const float* __restrict__ bg,
    const float* __restrict__ W0,
    unsigned short* __restrict__ W1t, unsigned short* __restrict__ W2t,
    unsigned short* __restrict__ W0f, float* __restrict__ bias0g)
{
    __shared__ float wl[128 * 17];
    const int mb  = blockIdx.x;
    const int tid = threadIdx.x;
    if (mb < 72) {
        const float* src = (mb < 64) ? (W1 + (size_t)mb * 2048)
                                     : (W2 + (size_t)(mb - 64) * 2048);
        unsigned short* dst = (mb < 64) ? (W1t + (size_t)mb * 2048)
                                        : (W2t + (size_t)(mb - 64) * 2048);
#pragma unroll
        for (int i = 0; i < 8; ++i) {
            const int idx = tid + i * 256;      // [k][h] in, coalesced
            wl[(idx >> 4) * 17 + (idx & 15)] = src[idx];
        }
        __syncthreads();
#pragma unroll
        for (int i = 0; i < 4; ++i) {
            const int u  = tid + i * 256;       // uint index over [h][k] bf16 out
            const int h  = u >> 6;
            const int k  = (u & 63) * 2;
            ((unsigned int*)dst)[u] = f2bf2(wl[k * 17 + h], wl[(k + 1) * 17 + h]);
        }
    } else {
        const int idx = mb - 72;                // 0..63, 8 modules each
        const int sub = tid >> 6, l = tid & 63;
#pragma unroll
        for (int it = 0; it < 2; ++it) {
            const int m = idx * 8 + it * 4 + sub;
            uint4 v = make_uint4(0u, 0u, 0u, 0u);
            if (l < 16) {
                float p[8];
                float bsum = 0.f;
#pragma unroll
                for (int j = 0; j < 8; ++j) {
                    const float w = W0[(size_t)m * 128 + j * 16 + l];
                    p[j] = Wg[m * 8 + j] * w;
                    bsum = fmaf(bg[m * 8 + j], w, bsum);
                }
                v.x = f2bf2(p[0], p[1]);
                v.y = f2bf2(p[2], p[3]);
                v.z = f2bf2(p[4], p[5]);
                v.w = f2bf2(p[6], p[7]);
                bias0g[m * 16 + l] = bsum;
            }
            *(uint4*)(W0f + (size_t)m * 512 + l * 8) = v;
        }
    }
}

// 2x4-deep software-pipeline regs for phase A (static indices only)
struct FragG { uint4 a0, a1, a2, a3; float4 b0, b1, b2, b3; };

__device__ __forceinline__ void load4(FragG& f, const unsigned short* w0fp,
                                      const float* bp, int g) {
    f.a0 = *(const uint4*)(w0fp + (size_t)(g * 4 + 0) * 512);
    f.a1 = *(const uint4*)(w0fp + (size_t)(g * 4 + 1) * 512);
    f.a2 = *(const uint4*)(w0fp + (size_t)(g * 4 + 2) * 512);
    f.a3 = *(const uint4*)(w0fp + (size_t)(g * 4 + 3) * 512);
    f.b0 = *(const float4*)(bp + (g * 4 + 0) * 16);
    f.b1 = *(const float4*)(bp + (g * 4 + 1) * 16);
    f.b2 = *(const float4*)(bp + (g * 4 + 2) * 16);
    f.b3 = *(const float4*)(bp + (g * 4 + 3) * 16);
}

__device__ __forceinline__ void comp4(const FragG& f, int g, int m0,
                                      const char* xrd, char* h0wr,
                                      int brow, int q) {
#pragma unroll
    for (int i = 0; i < 4; ++i) {
        const uint4  a4 = (i == 0) ? f.a0 : (i == 1) ? f.a1 : (i == 2) ? f.a2 : f.a3;
        const float4 b4 = (i == 0) ? f.b0 : (i == 1) ? f.b1 : (i == 2) ? f.b2 : f.b3;
        const int mloc = m0 + g * 4 + i;
        const short8 bv = *(const short8*)(xrd + ((mloc * 16) ^ ((brow & 7) << 4)));
        floatx4 acc = {b4.x, b4.y, b4.z, b4.w};
        acc = __builtin_amdgcn_mfma_f32_16x16x32_bf16(
                  __builtin_bit_cast(short8, a4), bv, acc, 0, 0, 0);
        *(uint2*)(h0wr + ((mloc * 32 + q * 8) ^ ((brow & 7) << 4))) =
            make_uint2(f2bf2(sigf(acc[0]), sigf(acc[1])),
                       f2bf2(sigf(acc[2]), sigf(acc[3])));
    }
}

__device__ __forceinline__ void phaseA(int s, int lane, int wv, int q,
    const unsigned short* __restrict__ W0f, const float* __restrict__ bias0g,
    const char* xsb, char* h0b)
{
    const int m0 = wv * 16;
    const unsigned short* w0fp = W0f + ((size_t)(s * 64 + m0) * 64 + lane) * 8;
    const float* bp = bias0g + (size_t)(s * 64 + m0) * 16 + q * 4;
    const int brow = lane & 15;
    const char* xrd = xsb + brow * 1024;
    char* h0wr = h0b + brow * 2048;
    FragG fA, fB;
    load4(fA, w0fp, bp, 0);
    load4(fB, w0fp, bp, 1);
    comp4(fA, 0, m0, xrd, h0wr, brow, q);
    load4(fA, w0fp, bp, 2);
    comp4(fB, 1, m0, xrd, h0wr, brow, q);
    load4(fB, w0fp, bp, 3);
    comp4(fA, 2, m0, xrd, h0wr, brow, q);
    comp4(fB, 3, m0, xrd, h0wr, brow, q);
}

__device__ __forceinline__ void phaseB(int n, int q, int wv,
    const short8 (&w1r)[2][4], const char* h0b, unsigned short* h1u)
{
    const int swn = (n & 7) << 4;              // read-side swizzle for row n
#pragma unroll
    for (int jj = 0; jj < 2; ++jj) {
        const int j = wv * 2 + jj;
        floatx4 acc = {0.f, 0.f, 0.f, 0.f};
#pragma unroll
        for (int ks = 0; ks < 4; ++ks) {
            const short8 av = *(const short8*)(h0b + n * 2048 +
                               ((j * 256 + q * 16 + ks * 64) ^ swn));
            acc = __builtin_amdgcn_mfma_f32_16x16x32_bf16(av, w1r[jj][ks], acc, 0, 0, 0);
        }
#pragma unroll
        for (int r = 0; r < 4; ++r)
            h1u[(q * 4 + r) * H1S + j * 16 + n] = f2bf(sigf(acc[r]));
    }
}

__device__ __forceinline__ void phaseC(int n, int q, int s, int b0,
    const short8 (&w2r)[4], const unsigned short* h1u, float* __restrict__ h2ws)
{
    const unsigned short* am = &h1u[n * H1S + q * 8];
    floatx4 acc = {0.f, 0.f, 0.f, 0.f};
#pragma unroll
    for (int ks = 0; ks < 4; ++ks) {
        const short8 av = *(const short8*)(am + ks * 32);
        acc = __builtin_amdgcn_mfma_f32_16x16x32_bf16(av, w2r[ks], acc, 0, 0, 0);
    }
#pragma unroll
    for (int r = 0; r < 4; ++r)
        h2ws[(size_t)(b0 + q * 4 + r) * 128 + s * 16 + n] = sigf(acc[r]);
}

__global__ __launch_bounds__(256, 3) void k_tree(
    const float* __restrict__ x,
    const unsigned short* __restrict__ W0f, const float* __restrict__ bias0g,
    const unsigned short* __restrict__ W1t, const unsigned short* __restrict__ W2t,
    float* __restrict__ h2ws)
{
    __shared__ __align__(16) unsigned short xs[16 * 512];     // 16384 B (h1 reuses)
    __shared__ __align__(16) unsigned short h0s[16 * 1024];   // 32768 B, swizzled
    unsigned short* h1u = xs;   // h1 [b][j*16+h] bf16, stride H1S; xs dead after A

    const int tid  = threadIdx.x;
    const int s    = blockIdx.x & 7;
    const int b0   = (blockIdx.x >> 3) * (2 * TB);   // two tiles per block
    const int b1   = b0 + TB;
    const int lane = tid & 63;
    const int wv   = tid >> 6;
    const int n    = lane & 15, q = lane >> 4;
    char* const xsb = (char*)xs;
    char* const h0b = (char*)h0s;

    // ---------- issue tile-0 x loads (oldest in pipe), convert as they land --
    const float* xbase0 = x + (size_t)b0 * 4096 + s * 512;
    uint2 xpA[8];
#pragma unroll
    for (int t = 0; t < 8; ++t) {
        const int i = tid + t * 256;           // over TB*128 float4s
        const int r = i >> 7, c4 = i & 127;
        const float4 v = *(const float4*)(xbase0 + (size_t)r * 4096 + c4 * 4);
        xpA[t] = make_uint2(f2bf2(v.x, v.y), f2bf2(v.z, v.w));
    }

    // ---------- prefetch phase-B/C MFMA B-fragments (reused for both tiles) --
    short8 w1r[2][4];
#pragma unroll
    for (int jj = 0; jj < 2; ++jj) {
        const unsigned short* w1m =
            W1t + ((size_t)(s * 8 + wv * 2 + jj) * 16 + n) * 128 + q * 8;
#pragma unroll
        for (int ks = 0; ks < 4; ++ks)
            w1r[jj][ks] = *(const short8*)(w1m + ks * 32);
    }
    short8 w2r[4];
    if (wv == 0) {
        const unsigned short* w2m = W2t + ((size_t)s * 16 + n) * 128 + q * 8;
#pragma unroll
        for (int ks = 0; ks < 4; ++ks) w2r[ks] = *(const short8*)(w2m + ks * 32);
    }

    // ---------- write tile-0 x to LDS (swizzled rows) ----------
#pragma unroll
    for (int t = 0; t < 8; ++t) {
        const int i = tid + t * 256;
        const int r = i >> 7, c4 = i & 127;
        *(uint2*)(xsb + r * 1024 + ((c4 * 8) ^ ((r & 7) << 4))) = xpA[t];
    }
    __syncthreads();

    // ---------- issue tile-1 x loads (raw); land under tile-0 compute -------
    const float* xbase1 = x + (size_t)b1 * 4096 + s * 512;
    float4 xrB[8];
#pragma unroll
    for (int t = 0; t < 8; ++t) {
        const int i = tid + t * 256;
        const int r = i >> 7, c4 = i & 127;
        xrB[t] = *(const float4*)(xbase1 + (size_t)r * 4096 + c4 * 4);
    }

    // ================= tile 0 =================
    phaseA(s, lane, wv, q, W0f, bias0g, xsb, h0b);
    __syncthreads();
    phaseB(n, q, wv, w1r, h0b, h1u);
    __syncthreads();
    if (wv == 0) phaseC(n, q, s, b0, w2r, h1u, h2ws);
    __syncthreads();                           // h1u (xs) free for tile-1 x

    // ---------- write tile-1 x to LDS ----------
#pragma unroll
    for (int t = 0; t < 8; ++t) {
        const int i = tid + t * 256;
        const int r = i >> 7, c4 = i & 127;
        *(uint2*)(xsb + r * 1024 + ((c4 * 8) ^ ((r & 7) << 4))) =
            make_uint2(f2bf2(xrB[t].x, xrB[t].y), f2bf2(xrB[t].z, xrB[t].w));
    }
    __syncthreads();

    // ================= tile 1 =================
    phaseA(s, lane, wv, q, W0f, bias0g, xsb, h0b);
    __syncthreads();
    phaseB(n, q, wv, w1r, h0b, h1u);
    __syncthreads();
    if (wv == 0) phaseC(n, q, s, b1, w2r, h1u, h2ws);
}

// ---------- kernel: root (128->16, sigmoid) + final dot(16) ----------
__global__ __launch_bounds__(256) void k_root(
    const float* __restrict__ h2ws, const float* __restrict__ W3,
    const float* __restrict__ Wf, float* __restrict__ out)
{
    __shared__ float w3s[2048];
    __shared__ float wfs[16];
    const int tid = threadIdx.x;
    *(float4*)&w3s[tid * 8]     = *(const float4*)(W3 + tid * 8);
    *(float4*)&w3s[tid * 8 + 4] = *(const float4*)(W3 + tid * 8 + 4);
    if (tid < 16) wfs[tid] = Wf[tid];
    __syncthreads();

    const int h = tid & 15;
    const int b = blockIdx.x * 16 + (tid >> 4);
    const float4* hp = (const float4*)(h2ws + (size_t)b * 128);
    float acc = 0.f;
#pragma unroll
    for (int k4 = 0; k4 < 32; ++k4) {
        const float4 hv = hp[k4];
        acc = fmaf(hv.x, w3s[(k4 * 4 + 0) * 16 + h], acc);
        acc = fmaf(hv.y, w3s[(k4 * 4 + 1) * 16 + h], acc);
        acc = fmaf(hv.z, w3s[(k4 * 4 + 2) * 16 + h], acc);
        acc = fmaf(hv.w, w3s[(k4 * 4 + 3) * 16 + h], acc);
    }
    float v = sigf(acc) * wfs[h];
    v += __shfl_down(v, 8, 16);
    v += __shfl_down(v, 4, 16);
    v += __shfl_down(v, 2, 16);
    v += __shfl_down(v, 1, 16);
    if (h == 0) out[b] = v;
}

extern "C" void kernel_launch(void* const* d_in, const int* in_sizes, int n_in,
                              void* d_out, int out_size, void* d_ws, size_t ws_size,
                              hipStream_t stream) {
    const float* x  = (const float*)d_in[0];
    const float* Wg = (const float*)d_in[1];
    const float* bg = (const float*)d_in[2];
    const float* W0 = (const float*)d_in[3];
    const float* W1 = (const float*)d_in[4];
    const float* W2 = (const float*)d_in[5];
    const float* W3 = (const float*)d_in[6];
    const float* Wf = (const float*)d_in[7];
    float* out = (float*)d_out;

    float* h2 = (float*)d_ws;                                          // 2 MB
    unsigned short* W1t = (unsigned short*)((char*)d_ws + (size_t)2 * 1024 * 1024); // 256 KB
    unsigned short* W2t = W1t + (size_t)64 * 2048;                                  //  32 KB
    unsigned short* W0f = (unsigned short*)((char*)d_ws + (size_t)2 * 1024 * 1024
                                                        + (size_t)512 * 1024);      // 512 KB
    float* bias0g = (float*)((char*)d_ws + (size_t)3 * 1024 * 1024);                //  32 KB

    k_prep<<<dim3(136), dim3(256), 0, stream>>>(W1, W2, Wg, bg, W0,
                                                W1t, W2t, W0f, bias0g);
    k_tree<<<dim3((4096 / TB / 2) * 8), dim3(256), 0, stream>>>(
        x, W0f, bias0g, W1t, W2t, h2);
    k_root<<<dim3(4096 / 16), dim3(256), 0, stream>>>(h2, W3, Wf, out);
}

// Round 10
// 119.409 us; speedup vs baseline: 1.1310x; 1.1310x over previous
//
#include <hip/hip_runtime.h>
#include <hip/hip_bf16.h>

// RestrictedNN DAG. Round 14: revert to R10b exactly (best, 117.6; six
// structural variants all regressed) + k_root ILP fix:
//  - k_root: 128 blocks, each thread owns TWO batch rows -> two independent
//    128-fmaf chains interleave (the serial chain was the latency floor).
//    Arithmetic per row identical -> absmax unchanged.
// B=4096, L0=512 leaves (G=8,H=16), L1=64, L2=8 (FAN=8), root 128->16.

#define TB 16
#define H1S 136      // ushorts per h1 row (128+8): rows 16B-aligned

typedef __attribute__((ext_vector_type(8))) short short8;
typedef __attribute__((ext_vector_type(4))) float floatx4;

__device__ __forceinline__ float sigf(float v) {
    return __builtin_amdgcn_rcpf(1.0f + __expf(-v));
}
// packed f32x2 -> bf16x2 (RNE). Compiler emits v_cvt_pk_bf16_f32.
__device__ __forceinline__ unsigned int f2bf2(float lo, float hi) {
    __hip_bfloat162 p = __float22bfloat162_rn(make_float2(lo, hi));
    unsigned int u;
    __builtin_memcpy(&u, &p, 4);
    return u;
}
__device__ __forceinline__ unsigned short f2bf(float f) {
    __hip_bfloat16 b = __float2bfloat16(f);
    unsigned short u;
    __builtin_memcpy(&u, &b, 2);
    return u;
}

// ---- prep ----
// blocks 0..71 : transpose W1/W2 per module to bf16 [h][k] fragment layout
// blocks 72..135: build W0f (per-module 64-lane A-frag table, bf16 Wg*W0,
//                zero K-pad) and bias0 (f32, = bg . W0)
__global__ __launch_bounds__(256) void k_prep(
    const float* __restrict__ W1, const float* __restrict__ W2,
    const float* __restrict__ Wg, const float* __restrict__ bg,
    const float* __restrict__ W0,
    unsigned short* __restrict__ W1t, unsigned short* __restrict__ W2t,
    unsigned short* __restrict__ W0f, float* __restrict__ bias0g)
{
    __shared__ float wl[128 * 17];
    const int mb  = blockIdx.x;
    const int tid = threadIdx.x;
    if (mb < 72) {
        const float* src = (mb < 64) ? (W1 + (size_t)mb * 2048)
                                     : (W2 + (size_t)(mb - 64) * 2048);
        unsigned short* dst = (mb < 64) ? (W1t + (size_t)mb * 2048)
                                        : (W2t + (size_t)(mb - 64) * 2048);
#pragma unroll
        for (int i = 0; i < 8; ++i) {
            const int idx = tid + i * 256;      // [k][h] in, coalesced
            wl[(idx >> 4) * 17 + (idx & 15)] = src[idx];
        }
        __syncthreads();
#pragma unroll
        for (int i = 0; i < 4; ++i) {
            const int u  = tid + i * 256;       // uint index over [h][k] bf16 out
            const int h  = u >> 6;
            const int k  = (u & 63) * 2;
            ((unsigned int*)dst)[u] = f2bf2(wl[k * 17 + h], wl[(k + 1) * 17 + h]);
        }
    } else {
        const int idx = mb - 72;                // 0..63, 8 modules each
        const int sub = tid >> 6, l = tid & 63;
#pragma unroll
        for (int it = 0; it < 2; ++it) {
            const int m = idx * 8 + it * 4 + sub;
            uint4 v = make_uint4(0u, 0u, 0u, 0u);
            if (l < 16) {
                float p[8];
                float bsum = 0.f;
#pragma unroll
                for (int j = 0; j < 8; ++j) {
                    const float w = W0[(size_t)m * 128 + j * 16 + l];
                    p[j] = Wg[m * 8 + j] * w;
                    bsum = fmaf(bg[m * 8 + j], w, bsum);
                }
                v.x = f2bf2(p[0], p[1]);
                v.y = f2bf2(p[2], p[3]);
                v.z = f2bf2(p[4], p[5]);
                v.w = f2bf2(p[6], p[7]);
                bias0g[m * 16 + l] = bsum;
            }
            *(uint4*)(W0f + (size_t)m * 512 + l * 8) = v;
        }
    }
}

// 2x4-deep software-pipeline regs for phase A (static indices only)
struct FragG { uint4 a0, a1, a2, a3; float4 b0, b1, b2, b3; };

__device__ __forceinline__ void load4(FragG& f, const unsigned short* w0fp,
                                      const float* bp, int g) {
    f.a0 = *(const uint4*)(w0fp + (size_t)(g * 4 + 0) * 512);
    f.a1 = *(const uint4*)(w0fp + (size_t)(g * 4 + 1) * 512);
    f.a2 = *(const uint4*)(w0fp + (size_t)(g * 4 + 2) * 512);
    f.a3 = *(const uint4*)(w0fp + (size_t)(g * 4 + 3) * 512);
    f.b0 = *(const float4*)(bp + (g * 4 + 0) * 16);
    f.b1 = *(const float4*)(bp + (g * 4 + 1) * 16);
    f.b2 = *(const float4*)(bp + (g * 4 + 2) * 16);
    f.b3 = *(const float4*)(bp + (g * 4 + 3) * 16);
}

__device__ __forceinline__ void comp4(const FragG& f, int g, int m0,
                                      const char* xrd, char* h0wr,
                                      int brow, int q) {
#pragma unroll
    for (int i = 0; i < 4; ++i) {
        const uint4  a4 = (i == 0) ? f.a0 : (i == 1) ? f.a1 : (i == 2) ? f.a2 : f.a3;
        const float4 b4 = (i == 0) ? f.b0 : (i == 1) ? f.b1 : (i == 2) ? f.b2 : f.b3;
        const int mloc = m0 + g * 4 + i;
        const short8 bv = *(const short8*)(xrd + ((mloc * 16) ^ ((brow & 7) << 4)));
        floatx4 acc = {b4.x, b4.y, b4.z, b4.w};
        acc = __builtin_amdgcn_mfma_f32_16x16x32_bf16(
                  __builtin_bit_cast(short8, a4), bv, acc, 0, 0, 0);
        *(uint2*)(h0wr + ((mloc * 32 + q * 8) ^ ((brow & 7) << 4))) =
            make_uint2(f2bf2(sigf(acc[0]), sigf(acc[1])),
                       f2bf2(sigf(acc[2]), sigf(acc[3])));
    }
}

__global__ __launch_bounds__(256, 3) void k_tree(
    const float* __restrict__ x,
    const unsigned short* __restrict__ W0f, const float* __restrict__ bias0g,
    const unsigned short* __restrict__ W1t, const unsigned short* __restrict__ W2t,
    float* __restrict__ h2ws)
{
    __shared__ __align__(16) unsigned short xs[16 * 512];     // 16384 B (h1 reuses)
    __shared__ __align__(16) unsigned short h0s[16 * 1024];   // 32768 B, swizzled
    unsigned short* h1u = xs;   // h1 [b][j*16+h] bf16, stride H1S; xs dead after A

    const int tid  = threadIdx.x;
    const int s    = blockIdx.x & 7;
    const int b0   = (blockIdx.x >> 3) * TB;
    const int lane = tid & 63;
    const int wv   = tid >> 6;
    const int n    = lane & 15, q = lane >> 4;

    // ---------- issue x stage loads (oldest in pipe), convert as they land ----
    const float* xbase = x + (size_t)b0 * 4096 + s * 512;
    uint2 xp[8];
#pragma unroll
    for (int t = 0; t < 8; ++t) {
        const int i = tid + t * 256;           // over TB*128 float4s
        const int r = i >> 7, c4 = i & 127;
        const float4 v = *(const float4*)(xbase + (size_t)r * 4096 + c4 * 4);
        xp[t] = make_uint2(f2bf2(v.x, v.y), f2bf2(v.z, v.w));
    }

    // ---------- prefetch phase-B/C MFMA B-fragments ----------
    short8 w1r[2][4];
#pragma unroll
    for (int jj = 0; jj < 2; ++jj) {
        const unsigned short* w1m =
            W1t + ((size_t)(s * 8 + wv * 2 + jj) * 16 + n) * 128 + q * 8;
#pragma unroll
        for (int ks = 0; ks < 4; ++ks)
            w1r[jj][ks] = *(const short8*)(w1m + ks * 32);
    }
    short8 w2r[4];
    if (wv == 0) {
        const unsigned short* w2m = W2t + ((size_t)s * 16 + n) * 128 + q * 8;
#pragma unroll
        for (int ks = 0; ks < 4; ++ks) w2r[ks] = *(const short8*)(w2m + ks * 32);
    }

    // ---------- write x tile to LDS (swizzled rows) ----------
#pragma unroll
    for (int t = 0; t < 8; ++t) {
        const int i = tid + t * 256;
        const int r = i >> 7, c4 = i & 127;
        *(uint2*)((char*)xs + r * 1024 + ((c4 * 8) ^ ((r & 7) << 4))) = xp[t];
    }
    __syncthreads();

    // ---------- phase A: one MFMA per leaf module ----------
    {
        const int m0 = wv * 16;
        const unsigned short* w0fp = W0f + ((size_t)(s * 64 + m0) * 64 + lane) * 8;
        const float* bp = bias0g + (size_t)(s * 64 + m0) * 16 + q * 4;
        const int brow = lane & 15;
        const char* xrd = (const char*)xs + brow * 1024;
        char* h0wr = (char*)h0s + brow * 2048;
        FragG fA, fB;
        load4(fA, w0fp, bp, 0);
        load4(fB, w0fp, bp, 1);
        comp4(fA, 0, m0, xrd, h0wr, brow, q);
        load4(fA, w0fp, bp, 2);
        comp4(fB, 1, m0, xrd, h0wr, brow, q);
        load4(fB, w0fp, bp, 3);
        comp4(fA, 2, m0, xrd, h0wr, brow, q);
        comp4(fB, 3, m0, xrd, h0wr, brow, q);
    }
    __syncthreads();

    // ---------- phase B: h1 MFMA. wave wv -> modules {2wv, 2wv+1} ----------
    {
        char* const h0b = (char*)h0s;
        const int swn = (n & 7) << 4;          // read-side swizzle for row n
#pragma unroll
        for (int jj = 0; jj < 2; ++jj) {
            const int j = wv * 2 + jj;
            floatx4 acc = {0.f, 0.f, 0.f, 0.f};
#pragma unroll
            for (int ks = 0; ks < 4; ++ks) {
                const short8 av = *(const short8*)(h0b + n * 2048 +
                                   ((j * 256 + q * 16 + ks * 64) ^ swn));
                acc = __builtin_amdgcn_mfma_f32_16x16x32_bf16(av, w1r[jj][ks], acc, 0, 0, 0);
            }
#pragma unroll
            for (int r = 0; r < 4; ++r)
                h1u[(q * 4 + r) * H1S + j * 16 + n] = f2bf(sigf(acc[r]));
        }
    }
    __syncthreads();

    // ---------- phase C: h2 MFMA (module s), wave 0 only ----------
    if (wv == 0) {
        const unsigned short* am = &h1u[n * H1S + q * 8];
        floatx4 acc = {0.f, 0.f, 0.f, 0.f};
#pragma unroll
        for (int ks = 0; ks < 4; ++ks) {
            const short8 av = *(const short8*)(am + ks * 32);
            acc = __builtin_amdgcn_mfma_f32_16x16x32_bf16(av, w2r[ks], acc, 0, 0, 0);
        }
#pragma unroll
        for (int r = 0; r < 4; ++r)
            h2ws[(size_t)(b0 + q * 4 + r) * 128 + s * 16 + n] = sigf(acc[r]);
    }
}

// ---------- kernel: root (128->16, sigmoid) + final dot(16) ----------
// 128 blocks; each thread owns TWO batch rows -> two independent fmaf
// chains interleave (ILP 2) instead of one serial 128-deep chain.
__global__ __launch_bounds__(256) void k_root(
    const float* __restrict__ h2ws, const float* __restrict__ W3,
    const float* __restrict__ Wf, float* __restrict__ out)
{
    __shared__ float w3s[2048];
    __shared__ float wfs[16];
    const int tid = threadIdx.x;
    *(float4*)&w3s[tid * 8]     = *(const float4*)(W3 + tid * 8);
    *(float4*)&w3s[tid * 8 + 4] = *(const float4*)(W3 + tid * 8 + 4);
    if (tid < 16) wfs[tid] = Wf[tid];
    __syncthreads();

    const int h  = tid & 15;
    const int bA = blockIdx.x * 32 + (tid >> 4);        // rows bA and bA+16
    const int bB = bA + 16;
    const float4* hpA = (const float4*)(h2ws + (size_t)bA * 128);
    const float4* hpB = (const float4*)(h2ws + (size_t)bB * 128);
    float accA = 0.f, accB = 0.f;
#pragma unroll
    for (int k4 = 0; k4 < 32; ++k4) {
        const float4 hA = hpA[k4];
        const float4 hB = hpB[k4];
        const float w0 = w3s[(k4 * 4 + 0) * 16 + h];
        const float w1 = w3s[(k4 * 4 + 1) * 16 + h];
        const float w2 = w3s[(k4 * 4 + 2) * 16 + h];
        const float w3v = w3s[(k4 * 4 + 3) * 16 + h];
        accA = fmaf(hA.x, w0, accA);  accB = fmaf(hB.x, w0, accB);
        accA = fmaf(hA.y, w1, accA);  accB = fmaf(hB.y, w1, accB);
        accA = fmaf(hA.z, w2, accA);  accB = fmaf(hB.z, w2, accB);
        accA = fmaf(hA.w, w3v, accA); accB = fmaf(hB.w, w3v, accB);
    }
    float vA = sigf(accA) * wfs[h];
    float vB = sigf(accB) * wfs[h];
    vA += __shfl_down(vA, 8, 16);
    vB += __shfl_down(vB, 8, 16);
    vA += __shfl_down(vA, 4, 16);
    vB += __shfl_down(vB, 4, 16);
    vA += __shfl_down(vA, 2, 16);
    vB += __shfl_down(vB, 2, 16);
    vA += __shfl_down(vA, 1, 16);
    vB += __shfl_down(vB, 1, 16);
    if (h == 0) { out[bA] = vA; out[bB] = vB; }
}

extern "C" void kernel_launch(void* const* d_in, const int* in_sizes, int n_in,
                              void* d_out, int out_size, void* d_ws, size_t ws_size,
                              hipStream_t stream) {
    const float* x  = (const float*)d_in[0];
    const float* Wg = (const float*)d_in[1];
    const float* bg = (const float*)d_in[2];
    const float* W0 = (const float*)d_in[3];
    const float* W1 = (const float*)d_in[4];
    const float* W2 = (const float*)d_in[5];
    const float* W3 = (const float*)d_in[6];
    const float* Wf = (const float*)d_in[7];
    float* out = (float*)d_out;

    float* h2 = (float*)d_ws;                                          // 2 MB
    unsigned short* W1t = (unsigned short*)((char*)d_ws + (size_t)2 * 1024 * 1024); // 256 KB
    unsigned short* W2t = W1t + (size_t)64 * 2048;                                  //  32 KB
    unsigned short* W0f = (unsigned short*)((char*)d_ws + (size_t)2 * 1024 * 1024
                                                        + (size_t)512 * 1024);      // 512 KB
    float* bias0g = (float*)((char*)d_ws + (size_t)3 * 1024 * 1024);                //  32 KB

    k_prep<<<dim3(136), dim3(256), 0, stream>>>(W1, W2, Wg, bg, W0,
                                                W1t, W2t, W0f, bias0g);
    k_tree<<<dim3((4096 / TB) * 8), dim3(256), 0, stream>>>(
        x, W0f, bias0g, W1t, W2t, h2);
    k_root<<<dim3(4096 / 32), dim3(256), 0, stream>>>(h2, W3, Wf, out);
}

// Round 11
// 117.830 us; speedup vs baseline: 1.1462x; 1.0134x over previous
//
#include <hip/hip_runtime.h>
#include <hip/hip_bf16.h>

// RestrictedNN DAG. Round 15 (FINAL): byte-exact resubmission of round 10b,
// the measured optimum (117.6 us). Eleven variants bracketed it:
//   - structural (mega-fusion, fence-root, sc-atomic-root, atomic-partial-root,
//     2-tile blocks): all regressed 2-180 us -> many small independent blocks
//     with natural inter-block overlap beat every explicit fusion scheme here.
//   - micro (occupancy 4/CU, k_root ILP-2): neutral at the +-1.5us noise floor.
// Composition: phase A on matrix pipe via folded Wg*W0 fragment table
// (h0pre = x·(Wg*W0) + bg·W0), v_cvt_pk_bf16_f32 packing, XOR-swizzled
// xs/h0s (^((row&7)<<4)), 3-kernel chain.
// B=4096, L0=512 leaves (G=8,H=16), L1=64, L2=8 (FAN=8), root 128->16.

#define TB 16
#define H1S 136      // ushorts per h1 row (128+8): rows 16B-aligned

typedef __attribute__((ext_vector_type(8))) short short8;
typedef __attribute__((ext_vector_type(4))) float floatx4;

__device__ __forceinline__ float sigf(float v) {
    return __builtin_amdgcn_rcpf(1.0f + __expf(-v));
}
// packed f32x2 -> bf16x2 (RNE). Compiler emits v_cvt_pk_bf16_f32.
__device__ __forceinline__ unsigned int f2bf2(float lo, float hi) {
    __hip_bfloat162 p = __float22bfloat162_rn(make_float2(lo, hi));
    unsigned int u;
    __builtin_memcpy(&u, &p, 4);
    return u;
}
__device__ __forceinline__ unsigned short f2bf(float f) {
    __hip_bfloat16 b = __float2bfloat16(f);
    unsigned short u;
    __builtin_memcpy(&u, &b, 2);
    return u;
}

// ---- prep ----
// blocks 0..71 : transpose W1/W2 per module to bf16 [h][k] fragment layout
// blocks 72..135: build W0f (per-module 64-lane A-frag table, bf16 Wg*W0,
//                zero K-pad) and bias0 (f32, = bg . W0)
__global__ __launch_bounds__(256) void k_prep(
    const float* __restrict__ W1, const float* __restrict__ W2,
    const float* __restrict__ Wg, const float* __restrict__ bg,
    const float* __restrict__ W0,
    unsigned short* __restrict__ W1t, unsigned short* __restrict__ W2t,
    unsigned short* __restrict__ W0f, float* __restrict__ bias0g)
{
    __shared__ float wl[128 * 17];
    const int mb  = blockIdx.x;
    const int tid = threadIdx.x;
    if (mb < 72) {
        const float* src = (mb < 64) ? (W1 + (size_t)mb * 2048)
                                     : (W2 + (size_t)(mb - 64) * 2048);
        unsigned short* dst = (mb < 64) ? (W1t + (size_t)mb * 2048)
                                        : (W2t + (size_t)(mb - 64) * 2048);
#pragma unroll
        for (int i = 0; i < 8; ++i) {
            const int idx = tid + i * 256;      // [k][h] in, coalesced
            wl[(idx >> 4) * 17 + (idx & 15)] = src[idx];
        }
        __syncthreads();
#pragma unroll
        for (int i = 0; i < 4; ++i) {
            const int u  = tid + i * 256;       // uint index over [h][k] bf16 out
            const int h  = u >> 6;
            const int k  = (u & 63) * 2;
            ((unsigned int*)dst)[u] = f2bf2(wl[k * 17 + h], wl[(k + 1) * 17 + h]);
        }
    } else {
        const int idx = mb - 72;                // 0..63, 8 modules each
        const int sub = tid >> 6, l = tid & 63;
#pragma unroll
        for (int it = 0; it < 2; ++it) {
            const int m = idx * 8 + it * 4 + sub;
            uint4 v = make_uint4(0u, 0u, 0u, 0u);
            if (l < 16) {
                float p[8];
                float bsum = 0.f;
#pragma unroll
                for (int j = 0; j < 8; ++j) {
                    const float w = W0[(size_t)m * 128 + j * 16 + l];
                    p[j] = Wg[m * 8 + j] * w;
                    bsum = fmaf(bg[m * 8 + j], w, bsum);
                }
                v.x = f2bf2(p[0], p[1]);
                v.y = f2bf2(p[2], p[3]);
                v.z = f2bf2(p[4], p[5]);
                v.w = f2bf2(p[6], p[7]);
                bias0g[m * 16 + l] = bsum;
            }
            *(uint4*)(W0f + (size_t)m * 512 + l * 8) = v;
        }
    }
}

// 2x4-deep software-pipeline regs for phase A (static indices only)
struct FragG { uint4 a0, a1, a2, a3; float4 b0, b1, b2, b3; };

__device__ __forceinline__ void load4(FragG& f, const unsigned short* w0fp,
                                      const float* bp, int g) {
    f.a0 = *(const uint4*)(w0fp + (size_t)(g * 4 + 0) * 512);
    f.a1 = *(const uint4*)(w0fp + (size_t)(g * 4 + 1) * 512);
    f.a2 = *(const uint4*)(w0fp + (size_t)(g * 4 + 2) * 512);
    f.a3 = *(const uint4*)(w0fp + (size_t)(g * 4 + 3) * 512);
    f.b0 = *(const float4*)(bp + (g * 4 + 0) * 16);
    f.b1 = *(const float4*)(bp + (g * 4 + 1) * 16);
    f.b2 = *(const float4*)(bp + (g * 4 + 2) * 16);
    f.b3 = *(const float4*)(bp + (g * 4 + 3) * 16);
}

__device__ __forceinline__ void comp4(const FragG& f, int g, int m0,
                                      const char* xrd, char* h0wr,
                                      int brow, int q) {
#pragma unroll
    for (int i = 0; i < 4; ++i) {
        const uint4  a4 = (i == 0) ? f.a0 : (i == 1) ? f.a1 : (i == 2) ? f.a2 : f.a3;
        const float4 b4 = (i == 0) ? f.b0 : (i == 1) ? f.b1 : (i == 2) ? f.b2 : f.b3;
        const int mloc = m0 + g * 4 + i;
        const short8 bv = *(const short8*)(xrd + ((mloc * 16) ^ ((brow & 7) << 4)));
        floatx4 acc = {b4.x, b4.y, b4.z, b4.w};
        acc = __builtin_amdgcn_mfma_f32_16x16x32_bf16(
                  __builtin_bit_cast(short8, a4), bv, acc, 0, 0, 0);
        *(uint2*)(h0wr + ((mloc * 32 + q * 8) ^ ((brow & 7) << 4))) =
            make_uint2(f2bf2(sigf(acc[0]), sigf(acc[1])),
                       f2bf2(sigf(acc[2]), sigf(acc[3])));
    }
}

__global__ __launch_bounds__(256, 3) void k_tree(
    const float* __restrict__ x,
    const unsigned short* __restrict__ W0f, const float* __restrict__ bias0g,
    const unsigned short* __restrict__ W1t, const unsigned short* __restrict__ W2t,
    float* __restrict__ h2ws)
{
    __shared__ __align__(16) unsigned short xs[16 * 512];     // 16384 B (h1 reuses)
    __shared__ __align__(16) unsigned short h0s[16 * 1024];   // 32768 B, swizzled
    unsigned short* h1u = xs;   // h1 [b][j*16+h] bf16, stride H1S; xs dead after A

    const int tid  = threadIdx.x;
    const int s    = blockIdx.x & 7;
    const int b0   = (blockIdx.x >> 3) * TB;
    const int lane = tid & 63;
    const int wv   = tid >> 6;
    const int n    = lane & 15, q = lane >> 4;

    // ---------- issue x stage loads (oldest in pipe), convert as they land ----
    const float* xbase = x + (size_t)b0 * 4096 + s * 512;
    uint2 xp[8];
#pragma unroll
    for (int t = 0; t < 8; ++t) {
        const int i = tid + t * 256;           // over TB*128 float4s
        const int r = i >> 7, c4 = i & 127;
        const float4 v = *(const float4*)(xbase + (size_t)r * 4096 + c4 * 4);
        xp[t] = make_uint2(f2bf2(v.x, v.y), f2bf2(v.z, v.w));
    }

    // ---------- prefetch phase-B/C MFMA B-fragments ----------
    short8 w1r[2][4];
#pragma unroll
    for (int jj = 0; jj < 2; ++jj) {
        const unsigned short* w1m =
            W1t + ((size_t)(s * 8 + wv * 2 + jj) * 16 + n) * 128 + q * 8;
#pragma unroll
        for (int ks = 0; ks < 4; ++ks)
            w1r[jj][ks] = *(const short8*)(w1m + ks * 32);
    }
    short8 w2r[4];
    if (wv == 0) {
        const unsigned short* w2m = W2t + ((size_t)s * 16 + n) * 128 + q * 8;
#pragma unroll
        for (int ks = 0; ks < 4; ++ks) w2r[ks] = *(const short8*)(w2m + ks * 32);
    }

    // ---------- write x tile to LDS (swizzled rows) ----------
#pragma unroll
    for (int t = 0; t < 8; ++t) {
        const int i = tid + t * 256;
        const int r = i >> 7, c4 = i & 127;
        *(uint2*)((char*)xs + r * 1024 + ((c4 * 8) ^ ((r & 7) << 4))) = xp[t];
    }
    __syncthreads();

    // ---------- phase A: one MFMA per leaf module ----------
    // wave wv owns local modules [wv*16, wv*16+16). Lane roles:
    //   A-frag: per-lane 16B row of W0f table (lanes>=16 hold zero K-pad)
    //   B-frag: x row (batch = lane&15), genes of module mloc
    //   D: col = batch = lane&15, rows h = q*4+r  -> one b64 write/module
    {
        const int m0 = wv * 16;
        const unsigned short* w0fp = W0f + ((size_t)(s * 64 + m0) * 64 + lane) * 8;
        const float* bp = bias0g + (size_t)(s * 64 + m0) * 16 + q * 4;
        const int brow = lane & 15;
        const char* xrd = (const char*)xs + brow * 1024;
        char* h0wr = (char*)h0s + brow * 2048;
        FragG fA, fB;
        load4(fA, w0fp, bp, 0);
        load4(fB, w0fp, bp, 1);
        comp4(fA, 0, m0, xrd, h0wr, brow, q);
        load4(fA, w0fp, bp, 2);
        comp4(fB, 1, m0, xrd, h0wr, brow, q);
        load4(fB, w0fp, bp, 3);
        comp4(fA, 2, m0, xrd, h0wr, brow, q);
        comp4(fB, 3, m0, xrd, h0wr, brow, q);
    }
    __syncthreads();

    // ---------- phase B: h1 MFMA. wave wv -> modules {2wv, 2wv+1} ----------
    {
        char* const h0b = (char*)h0s;
        const int swn = (n & 7) << 4;          // read-side swizzle for row n
#pragma unroll
        for (int jj = 0; jj < 2; ++jj) {
            const int j = wv * 2 + jj;
            floatx4 acc = {0.f, 0.f, 0.f, 0.f};
#pragma unroll
            for (int ks = 0; ks < 4; ++ks) {
                const short8 av = *(const short8*)(h0b + n * 2048 +
                                   ((j * 256 + q * 16 + ks * 64) ^ swn));
                acc = __builtin_amdgcn_mfma_f32_16x16x32_bf16(av, w1r[jj][ks], acc, 0, 0, 0);
            }
#pragma unroll
            for (int r = 0; r < 4; ++r)
                h1u[(q * 4 + r) * H1S + j * 16 + n] = f2bf(sigf(acc[r]));
        }
    }
    __syncthreads();

    // ---------- phase C: h2 MFMA (module s), wave 0 only ----------
    if (wv == 0) {
        const unsigned short* am = &h1u[n * H1S + q * 8];
        floatx4 acc = {0.f, 0.f, 0.f, 0.f};
#pragma unroll
        for (int ks = 0; ks < 4; ++ks) {
            const short8 av = *(const short8*)(am + ks * 32);
            acc = __builtin_amdgcn_mfma_f32_16x16x32_bf16(av, w2r[ks], acc, 0, 0, 0);
        }
#pragma unroll
        for (int r = 0; r < 4; ++r)
            h2ws[(size_t)(b0 + q * 4 + r) * 128 + s * 16 + n] = sigf(acc[r]);
    }
}

// ---------- kernel: root (128->16, sigmoid) + final dot(16) ----------
__global__ __launch_bounds__(256) void k_root(
    const float* __restrict__ h2ws, const float* __restrict__ W3,
    const float* __restrict__ Wf, float* __restrict__ out)
{
    __shared__ float w3s[2048];
    __shared__ float wfs[16];
    const int tid = threadIdx.x;
    *(float4*)&w3s[tid * 8]     = *(const float4*)(W3 + tid * 8);
    *(float4*)&w3s[tid * 8 + 4] = *(const float4*)(W3 + tid * 8 + 4);
    if (tid < 16) wfs[tid] = Wf[tid];
    __syncthreads();

    const int h = tid & 15;
    const int b = blockIdx.x * 16 + (tid >> 4);
    const float4* hp = (const float4*)(h2ws + (size_t)b * 128);
    float acc = 0.f;
#pragma unroll
    for (int k4 = 0; k4 < 32; ++k4) {
        const float4 hv = hp[k4];
        acc = fmaf(hv.x, w3s[(k4 * 4 + 0) * 16 + h], acc);
        acc = fmaf(hv.y, w3s[(k4 * 4 + 1) * 16 + h], acc);
        acc = fmaf(hv.z, w3s[(k4 * 4 + 2) * 16 + h], acc);
        acc = fmaf(hv.w, w3s[(k4 * 4 + 3) * 16 + h], acc);
    }
    float v = sigf(acc) * wfs[h];
    v += __shfl_down(v, 8, 16);
    v += __shfl_down(v, 4, 16);
    v += __shfl_down(v, 2, 16);
    v += __shfl_down(v, 1, 16);
    if (h == 0) out[b] = v;
}

extern "C" void kernel_launch(void* const* d_in, const int* in_sizes, int n_in,
                              void* d_out, int out_size, void* d_ws, size_t ws_size,
                              hipStream_t stream) {
    const float* x  = (const float*)d_in[0];
    const float* Wg = (const float*)d_in[1];
    const float* bg = (const float*)d_in[2];
    const float* W0 = (const float*)d_in[3];
    const float* W1 = (const float*)d_in[4];
    const float* W2 = (const float*)d_in[5];
    const float* W3 = (const float*)d_in[6];
    const float* Wf = (const float*)d_in[7];
    float* out = (float*)d_out;

    float* h2 = (float*)d_ws;                                          // 2 MB
    unsigned short* W1t = (unsigned short*)((char*)d_ws + (size_t)2 * 1024 * 1024); // 256 KB
    unsigned short* W2t = W1t + (size_t)64 * 2048;                                  //  32 KB
    unsigned short* W0f = (unsigned short*)((char*)d_ws + (size_t)2 * 1024 * 1024
                                                        + (size_t)512 * 1024);      // 512 KB
    float* bias0g = (float*)((char*)d_ws + (size_t)3 * 1024 * 1024);                //  32 KB

    k_prep<<<dim3(136), dim3(256), 0, stream>>>(W1, W2, Wg, bg, W0,
                                                W1t, W2t, W0f, bias0g);
    k_tree<<<dim3((4096 / TB) * 8), dim3(256), 0, stream>>>(
        x, W0f, bias0g, W1t, W2t, h2);
    k_root<<<dim3(4096 / 16), dim3(256), 0, stream>>>(h2, W3, Wf, out);
}